// Round 3
// baseline (242.538 us; speedup 1.0000x reference)
//
#include <hip/hip_runtime.h>
#include <math.h>

#define VOCAB 2048
#define EMB 256
#define MAXLEN 8
#define NBATCH 16
#define LAT 16
#define NG4 8192      // 4*VOCAB
#define UB 16         // u-blocks: 128 u per gate per block
#define JCW 32        // Wr row-chunks of 64
#define KCX 4         // Wk row-chunks of 64

// token = argmax_j ( j/2048 <= v && v <= (j+1)/2048 ), 0 if none.
// cumsum of uniform softmax is exactly k/2048 in fp32; v*2048 is exact.
__device__ __forceinline__ int token_of(float v) {
    float u = v * 2048.0f;
    if (!(u >= 0.0f) || u > 2048.0f) return 0;   // v<0, v>1, or NaN
    int k = (int)ceilf(u) - 1;
    return k < 0 ? 0 : k;
}

__device__ __forceinline__ float sigmoidf_(float x) { return 1.0f / (1.0f + expf(-x)); }

// ---- Kernel A: XT[t][k][b] = E[token(b,t)][k]; zero h, c ----
__global__ void k_init(const float* __restrict__ ip, const float* __restrict__ E,
                       float* __restrict__ XT, float* __restrict__ h, float* __restrict__ c) {
    int idx = blockIdx.x * 256 + threadIdx.x;   // 0..32767
    int t = idx >> 12;
    int b = (idx >> 8) & 15;
    int k = idx & 255;
    int tok = token_of(ip[b * LAT + t]);
    XT[t * (EMB * NBATCH) + k * NBATCH + b] = E[tok * EMB + k];
    h[idx] = 0.0f;
    c[idx] = 0.0f;
}

// ---- Kernel B: xz partials for ALL timesteps (off critical path).
// grid = KCX*8*UB blocks of 256. block (kc,t,ub); wave g=tid>>6; u=ub*128+lane*2.
// xzp[((kc*8+t)*16+b)*NG4 + g*2048+u] = sum_{jl} Wk[kc*64+jl][g*2048+u] * XT[t][kc*64+jl][b]
// bias folded into kc==0.
__global__ __launch_bounds__(256) void k_xz(
        const float* __restrict__ Wk, const float* __restrict__ XT,
        const float* __restrict__ bv, float* __restrict__ xzp) {
    int bx = blockIdx.x;
    int ub = bx & (UB - 1);
    int t  = (bx >> 4) & 7;
    int kc = bx >> 7;
    int g = threadIdx.x >> 6;
    int lane = threadIdx.x & 63;
    int u = ub * 128 + lane * 2;

    const float* wp = Wk + (size_t)(kc * 64) * NG4 + g * 2048 + u;
    const float4* xp = (const float4*)(XT + (t * EMB + kc * 64) * NBATCH);

    float2 binit = make_float2(0.f, 0.f);
    if (kc == 0) binit = *(const float2*)&bv[g * 2048 + u];

    float2 acc[NBATCH];
    #pragma unroll
    for (int b = 0; b < NBATCH; ++b) acc[b] = binit;

    #pragma unroll 4
    for (int jl = 0; jl < 64; ++jl) {
        float2 w = *(const float2*)(wp + (size_t)jl * NG4);
        float4 x0 = xp[jl * 4 + 0];
        float4 x1 = xp[jl * 4 + 1];
        float4 x2 = xp[jl * 4 + 2];
        float4 x3 = xp[jl * 4 + 3];
        float xb[NBATCH] = {x0.x,x0.y,x0.z,x0.w, x1.x,x1.y,x1.z,x1.w,
                            x2.x,x2.y,x2.z,x2.w, x3.x,x3.y,x3.z,x3.w};
        #pragma unroll
        for (int b = 0; b < NBATCH; ++b) {
            acc[b].x = fmaf(w.x, xb[b], acc[b].x);
            acc[b].y = fmaf(w.y, xb[b], acc[b].y);
        }
    }
    #pragma unroll
    for (int b = 0; b < NBATCH; ++b)
        *(float2*)&xzp[(size_t)(((kc * 8 + t) * NBATCH) + b) * NG4 + g * 2048 + u] = acc[b];
}

// ---- Kernel C: Wr partials from hT (uniform-address broadcast, no LDS).
// grid = JCW*UB blocks of 256. block (jc,ub); wave g; u=ub*128+lane*2.
__global__ __launch_bounds__(256) void k_gemm(
        const float* __restrict__ Wr, const float* __restrict__ hT,
        float* __restrict__ zp) {
    int bx = blockIdx.x;
    int ub = bx & (UB - 1);
    int jc = bx >> 4;
    int g = threadIdx.x >> 6;
    int lane = threadIdx.x & 63;
    int u = ub * 128 + lane * 2;

    const float* wp = Wr + (size_t)(jc * 64) * NG4 + g * 2048 + u;
    const float4* hp = (const float4*)(hT + jc * 64 * NBATCH);

    float2 acc[NBATCH];
    #pragma unroll
    for (int b = 0; b < NBATCH; ++b) acc[b] = make_float2(0.f, 0.f);

    #pragma unroll 4
    for (int jl = 0; jl < 64; ++jl) {
        float2 w = *(const float2*)(wp + (size_t)jl * NG4);
        float4 h0 = hp[jl * 4 + 0];
        float4 h1 = hp[jl * 4 + 1];
        float4 h2 = hp[jl * 4 + 2];
        float4 h3 = hp[jl * 4 + 3];
        float hb[NBATCH] = {h0.x,h0.y,h0.z,h0.w, h1.x,h1.y,h1.z,h1.w,
                            h2.x,h2.y,h2.z,h2.w, h3.x,h3.y,h3.z,h3.w};
        #pragma unroll
        for (int b = 0; b < NBATCH; ++b) {
            acc[b].x = fmaf(w.x, hb[b], acc[b].x);
            acc[b].y = fmaf(w.y, hb[b], acc[b].y);
        }
    }
    #pragma unroll
    for (int b = 0; b < NBATCH; ++b)
        *(float2*)&zp[(size_t)(jc * NBATCH + b) * NG4 + g * 2048 + u] = acc[b];
}

// ---- Kernel D: reduce partials, gates, masked state update, write h/hT/H[t].
// grid = 128 blocks x 256: thread -> (b,u).
__global__ __launch_bounds__(256) void k_update(
        const float* __restrict__ zp, const float* __restrict__ xzp,
        const float* __restrict__ ip, float* __restrict__ h, float* __restrict__ hT,
        float* __restrict__ c, float* __restrict__ H, int t) {
    int idx = blockIdx.x * 256 + threadIdx.x;   // 0..32767
    int b = idx >> 11;
    int u = idx & 2047;

    float z[4] = {0.f, 0.f, 0.f, 0.f};
    #pragma unroll
    for (int kc = 0; kc < KCX; ++kc) {
        const float* p = xzp + (size_t)((kc * 8 + t) * NBATCH + b) * NG4 + u;
        #pragma unroll
        for (int g = 0; g < 4; ++g) z[g] += p[g * 2048];
    }
    if (t > 0) {
        #pragma unroll
        for (int jc = 0; jc < JCW; ++jc) {
            const float* p = zp + (size_t)(jc * NBATCH + b) * NG4 + u;
            #pragma unroll
            for (int g = 0; g < 4; ++g) z[g] += p[g * 2048];
        }
    }

    float co = c[idx], ho = h[idx];
    float cn = sigmoidf_(z[1]) * co + sigmoidf_(z[0]) * tanhf(z[2]);
    float hn = sigmoidf_(z[3]) * tanhf(cn);
    int tok = token_of(ip[b * LAT + t]);
    float hw = tok != 0 ? hn : ho;
    float cw = tok != 0 ? cn : co;
    h[idx] = hw;
    c[idx] = cw;
    hT[u * NBATCH + b] = hw;
    H[(size_t)t * (NBATCH * VOCAB) + idx] = hw;
}

// ---- Kernel E: softmax of all 128 recorded h rows -> d_out[b][t][:] ----
__global__ __launch_bounds__(256) void k_softmax(const float* __restrict__ H,
                                                 float* __restrict__ out) {
    int r = blockIdx.x;          // r = t*16 + b
    int t = r >> 4, b = r & 15;
    int tid = threadIdx.x;
    const float* hr = H + (size_t)r * VOCAB;
    float v[8];
    float m = -1e30f;
    #pragma unroll
    for (int i = 0; i < 8; ++i) { v[i] = hr[tid + i * 256]; m = fmaxf(m, v[i]); }

    __shared__ float redm[4], reds[4];
    int wid = tid >> 6, lane = tid & 63;
    #pragma unroll
    for (int off = 32; off; off >>= 1) m = fmaxf(m, __shfl_down(m, off));
    if (lane == 0) redm[wid] = m;
    __syncthreads();
    m = fmaxf(fmaxf(redm[0], redm[1]), fmaxf(redm[2], redm[3]));

    float e[8];
    float s = 0.0f;
    #pragma unroll
    for (int i = 0; i < 8; ++i) { e[i] = expf(v[i] - m); s += e[i]; }
    #pragma unroll
    for (int off = 32; off; off >>= 1) s += __shfl_down(s, off);
    if (lane == 0) reds[wid] = s;
    __syncthreads();
    s = reds[0] + reds[1] + reds[2] + reds[3];

    float* o = out + ((size_t)b * MAXLEN + t) * VOCAB;
    #pragma unroll
    for (int i = 0; i < 8; ++i) o[tid + i * 256] = e[i] / s;
}

extern "C" void kernel_launch(void* const* d_in, const int* in_sizes, int n_in,
                              void* d_out, int out_size, void* d_ws, size_t ws_size,
                              hipStream_t stream) {
    const float* ip = (const float*)d_in[0];   // (16,16)
    const float* E  = (const float*)d_in[1];   // (2048,256)
    const float* Wk = (const float*)d_in[2];   // (256,8192)
    const float* Wr = (const float*)d_in[3];   // (2048,8192)
    const float* bv = (const float*)d_in[4];   // (8192,)

    float* ws  = (float*)d_ws;
    float* XT  = ws;              // 8*256*16   = 32768
    float* h   = XT + 32768;      // 16*2048    = 32768
    float* hT  = h  + 32768;      // 2048*16    = 32768
    float* c   = hT + 32768;      // 16*2048    = 32768
    float* H   = c  + 32768;      // 8*16*2048  = 262144
    float* xzp = H  + 262144;     // 4*8*16*8192 = 4194304 (~16.8 MB)
    float* zp  = xzp + 4194304;   // 32*16*8192  = 4194304 (~16.8 MB)

    k_init<<<128, 256, 0, stream>>>(ip, E, XT, h, c);
    k_xz<<<KCX * 8 * UB, 256, 0, stream>>>(Wk, XT, bv, xzp);
    for (int t = 0; t < MAXLEN; ++t) {
        if (t > 0)
            k_gemm<<<JCW * UB, 256, 0, stream>>>(Wr, hT, zp);
        k_update<<<128, 256, 0, stream>>>(zp, xzp, ip, h, hT, c, H, t);
    }
    k_softmax<<<128, 256, 0, stream>>>(H, (float*)d_out);
}